// Round 11
// baseline (179.574 us; speedup 1.0000x reference)
//
#include <hip/hip_runtime.h>
#include <hip/hip_bf16.h>
#include <math.h>

#define VOCAB 100000
#define TOPK  20
#define EMB   300
#define NTOK  (64*256)
#define NB    1563          // ceil(VOCAB/64) v-tiles
#define NVG   96            // v-groups (blocks per e-slice)
#define NESL  5             // e-slices of 64 cols

typedef __attribute__((ext_vector_type(8))) short short8;   // 8 bf16 = 4 VGPR
typedef __attribute__((ext_vector_type(4))) short short4v;  // 8 B
typedef __attribute__((ext_vector_type(4))) float f32x4;

static __device__ inline short f2bf(float f) {
    __hip_bfloat16 h = __float2bfloat16(f);
    short s; __builtin_memcpy(&s, &h, 2);
    return s;
}

// XOR swizzle over 38-chunk rows: full 8-way for chunks 0..31, 4-way for
// 32..35, 2-way for 36..37 (keeps every region in-bounds & bijective per row).
static __device__ inline int swz(int q, int r) {
    return q < 32 ? (q ^ (r & 7))
         : q < 36 ? (32 + ((q & 3) ^ (r & 3)))
                  : (36 + ((q & 1) ^ (r & 1)));
}

// ---------------------------------------------------------------------------
// prep: aT[e][d] = bf16(a[d][e]), zero-padded to 320x320.
// ---------------------------------------------------------------------------
__global__ void prep_kernel(const float* __restrict__ A, short* __restrict__ aT)
{
    const int e = blockIdx.x;                 // 0..319
    for (int d = threadIdx.x; d < 320; d += 256) {
        float f = (e < EMB && d < EMB) ? A[(size_t)d * EMB + e] : 0.f;
        aT[e * 320 + d] = f2bf(f);
    }
}

// ---------------------------------------------------------------------------
// score: s[v] = sum_e tanh( emb[v,:] . a[:,e] ) * b[e]  via bf16 MFMA.
// Designed INSIDE the observed 128-VGPR cap (r8-r10: every knob left the
// allocator at 128 + spills). Block = (e-slice of 64 cols, v-group),
// persistent over ~16 v-tiles. LDS: B-slice 38 KB (k-chunks 0..37 only;
// 38/39 are zero-pad handled by a zero-reg guard) + A-tile 38 KB + Sred
// = 78.3 KB  ->  2 blocks/CU (4 waves/SIMD) so phases of the two blocks
// overlap. Registers: acc[2][2]=16 + frag dbuf 32 + pf 44 ~= 110 < 128.
// A-stream x5 e-slice duplication is served from L2 by XCD-grouping: the 5
// slice-blocks of a v-group share bid%8 (same XCD), walk the same A-tiles
// in lockstep -> each tile L2-fetched once, read 5x.
// Waves: 2mg x 2ng x 2kh; wave = 32 rows x 32 cols x k-half(160).
// S output: 5 partial planes, summed by attend (no cross-block sync).
// ---------------------------------------------------------------------------
__global__ __launch_bounds__(512, 2) void score_kernel(
    const float* __restrict__ emb, const short* __restrict__ aT,
    const float* __restrict__ B, float* __restrict__ S)
{
    __shared__ short8 EsS[64 * 38];      // 38912 B : A tile (Scr overlays)
    __shared__ short8 BsS[64 * 38];      // 38912 B : B slice, block-stationary
    __shared__ float  Sred[128];         // 512 B

    const int t   = threadIdx.x;
    const int bid = blockIdx.x;
    const int low = bid % 40;
    const int esl = low >> 3;                  // 0..4
    const int vg  = (bid / 40) * 8 + (low & 7);// 0..95

    // ---- one-time: stage B-slice (64 local cols x 38 chunks) from L2 aT
    const short8* aT8 = (const short8*)aT;
    for (int i = t; i < 64 * 38; i += 512) {
        const int col = i / 38, kc = i - col * 38;
        BsS[col * 38 + swz(kc, col)] = aT8[(esl * 64 + col) * 40 + kc];
    }

    const int lid = t & 63;
    const int w   = t >> 6;        // 0..7
    const int kh  = w >> 2;        // k-half 0..1
    const int mg  = (w >> 1) & 1;  // m-pair (rows mg*32..mg*32+31)
    const int ng  = w & 1;         // n-pair (cols ng*32..ng*32+31)
    const int lm  = lid & 15;
    const int lk  = lid >> 4;
    const int kb  = kh * 20;       // k-chunk base
    const int cell = mg * 2 + ng;

    float bcol[2];
    int rbA[2], rbB[2];
#pragma unroll
    for (int n = 0; n < 2; ++n) {
        const int col = ng * 32 + n * 16 + lm;       // local col
        rbB[n] = col * 38;
        const int e = esl * 64 + col;
        bcol[n] = (e < EMB) ? B[e] : 0.f;
    }
#pragma unroll
    for (int mt = 0; mt < 2; ++mt)
        rbA[mt] = (mg * 32 + mt * 16 + lm) * 38;
    // row%8 == col%8 == lm%8 (tile offsets are multiples of 16) -> swz(q, lm)

    const int ntiles = (NB - vg + NVG - 1) / NVG;

    float4 pf[5][2]; float4 pft;

#define ISSUE_PF(TT) do {                                                     \
    const float4* esrc = (const float4*)(emb + (size_t)(TT) * 64 * EMB);      \
    _Pragma("unroll")                                                         \
    for (int j = 0; j < 5; ++j) {                                             \
        const int i = t + j * 512;                                            \
        const int row = i / 37, c = i - row * 37;                             \
        const bool ok = (i < 2368) && ((TT) * 64 + row < VOCAB);              \
        pf[j][0] = ok ? esrc[row * 75 + c * 2]     : make_float4(0,0,0,0);    \
        pf[j][1] = ok ? esrc[row * 75 + c * 2 + 1] : make_float4(0,0,0,0);    \
    }                                                                         \
    if (t < 64) pft = ((TT) * 64 + t < VOCAB) ? esrc[t * 75 + 74]             \
                                              : make_float4(0,0,0,0);         \
} while (0)

#define STAGE() do {                                                          \
    _Pragma("unroll")                                                         \
    for (int j = 0; j < 5; ++j) {                                             \
        const int i = t + j * 512;                                            \
        if (i < 2368) {                                                       \
            const int row = i / 37, c = i - row * 37;                         \
            short8 val;                                                       \
            val[0]=f2bf(pf[j][0].x); val[1]=f2bf(pf[j][0].y);                 \
            val[2]=f2bf(pf[j][0].z); val[3]=f2bf(pf[j][0].w);                 \
            val[4]=f2bf(pf[j][1].x); val[5]=f2bf(pf[j][1].y);                 \
            val[6]=f2bf(pf[j][1].z); val[7]=f2bf(pf[j][1].w);                 \
            EsS[row * 38 + swz(c, row)] = val;                                \
        }                                                                     \
    }                                                                         \
    if (t < 64) {                                                             \
        short4v h; h.x=f2bf(pft.x); h.y=f2bf(pft.y);                          \
        h.z=f2bf(pft.z); h.w=f2bf(pft.w);                                     \
        short* base = (short*)&EsS[t * 38 + swz(37, t)];                      \
        *(short4v*)(base) = h;                                                \
        *(short4v*)(base + 4) = (short4v){0, 0, 0, 0};                        \
    }                                                                         \
} while (0)

    // prologue: load + stage tile 0 (B-stage covered by first barrier too)
    ISSUE_PF(vg);
    STAGE();

    for (int tt = 0; tt < ntiles; ++tt) {
        const int T  = vg + tt * NVG;
        const int v0 = T * 64;

        __syncthreads();                           // B1: EsS (+BsS) ready
        if (tt + 1 < ntiles) ISSUE_PF(vg + (tt + 1) * NVG);

        // ---- k-loop: 5 steps, reg-dbuf'd LDS frags, 4 MFMA/step
        f32x4 acc[2][2];
#pragma unroll
        for (int mt = 0; mt < 2; ++mt)
#pragma unroll
            for (int n = 0; n < 2; ++n)
                acc[mt][n] = (f32x4){0.f, 0.f, 0.f, 0.f};

        short8 afr[2][2], bfr[2][2];
        {
            const int sx = swz(kb + lk, lm);
            afr[0][0] = EsS[rbA[0] + sx];
            afr[0][1] = EsS[rbA[1] + sx];
            bfr[0][0] = BsS[rbB[0] + sx];
            bfr[0][1] = BsS[rbB[1] + sx];
        }
#pragma unroll
        for (int ks = 0; ks < 5; ++ks) {
            const int cur = ks & 1, nx = cur ^ 1;
            if (ks < 4) {
                const int q  = kb + (ks + 1) * 4 + lk;
                const int sx = swz(q, lm);
                const bool zz = (q >= 38);         // zero-pad chunks 38/39
                const short8 z8 = (short8){0,0,0,0,0,0,0,0};
                afr[nx][0] = zz ? z8 : EsS[rbA[0] + sx];
                afr[nx][1] = zz ? z8 : EsS[rbA[1] + sx];
                bfr[nx][0] = zz ? z8 : BsS[rbB[0] + sx];
                bfr[nx][1] = zz ? z8 : BsS[rbB[1] + sx];
            }
#pragma unroll
            for (int mt = 0; mt < 2; ++mt)
#pragma unroll
                for (int n = 0; n < 2; ++n)
                    acc[mt][n] = __builtin_amdgcn_mfma_f32_16x16x32_bf16(
                                     afr[cur][mt], bfr[cur][n], acc[mt][n], 0, 0, 0);
        }
        __syncthreads();                           // B2: EsS/BsS reads done

        // ---- kh-exchange via Scr overlaying EsS (pre-tanh partial sums)
        float4* Scr = (float4*)EsS;                // [4 mtn][4 cell][64 lane]
        if (kh == 1) {
#pragma unroll
            for (int mt = 0; mt < 2; ++mt)
#pragma unroll
                for (int n = 0; n < 2; ++n)
                    Scr[((mt * 2 + n) * 4 + cell) * 64 + lid] = *(float4*)&acc[mt][n];
        }
        __syncthreads();                           // B3: partials shipped

        if (kh == 0) {
            float part[2][4];
#pragma unroll
            for (int mt = 0; mt < 2; ++mt) {
                float4 o0 = Scr[((mt * 2 + 0) * 4 + cell) * 64 + lid];
                float4 o1 = Scr[((mt * 2 + 1) * 4 + cell) * 64 + lid];
#pragma unroll
                for (int i = 0; i < 4; ++i) {
                    float x0 = acc[mt][0][i] + (&o0.x)[i];
                    float x1 = acc[mt][1][i] + (&o1.x)[i];
                    float c0 = fminf(fmaxf(x0, -15.f), 15.f);
                    float c1 = fminf(fmaxf(x1, -15.f), 15.f);
                    float e0 = __expf(2.f * c0);
                    float e1 = __expf(2.f * c1);
                    part[mt][i] = __fdividef(e0 - 1.f, e0 + 1.f) * bcol[0]
                                + __fdividef(e1 - 1.f, e1 + 1.f) * bcol[1];
                }
            }
#pragma unroll
            for (int m = 1; m <= 8; m <<= 1)
#pragma unroll
                for (int mt = 0; mt < 2; ++mt)
#pragma unroll
                    for (int i = 0; i < 4; ++i)
                        part[mt][i] += __shfl_xor(part[mt][i], m);
            if (lm == 0) {
#pragma unroll
                for (int mt = 0; mt < 2; ++mt)
#pragma unroll
                    for (int i = 0; i < 4; ++i)
                        Sred[ng * 64 + mg * 32 + mt * 16 + lk * 4 + i] = part[mt][i];
            }
        }
        __syncthreads();                           // B4: Sred ready, Scr free

        if (t < 64) {
            const int v = v0 + t;
            if (v < VOCAB) S[esl * VOCAB + v] = Sred[t] + Sred[64 + t];
        }
        if (tt + 1 < ntiles) STAGE();              // overwrite EsS for next B1
    }
#undef ISSUE_PF
#undef STAGE
}

// ---------------------------------------------------------------------------
// attend: per token gather 20 neighbor scores (sum of 5 slice planes),
// softmax, weighted emb sum. One wave per token.
// ---------------------------------------------------------------------------
__global__ __launch_bounds__(256) void attend_kernel(
    const int* __restrict__ text, const int* __restrict__ neighbors,
    const float* __restrict__ emb, const float* __restrict__ S,
    float* __restrict__ out)
{
    const int lane = threadIdx.x & 63;
    const int wv   = threadIdx.x >> 6;
    const int tok  = blockIdx.x * 4 + wv;

    const int tid = text[tok];

    int   nbk = 0;
    float sc  = -1e30f;
    if (lane < TOPK) {
        nbk = neighbors[tid * TOPK + lane];
        sc  = S[nbk] + S[VOCAB + nbk] + S[2 * VOCAB + nbk]
            + S[3 * VOCAB + nbk] + S[4 * VOCAB + nbk];
    }

    float mx = sc;
#pragma unroll
    for (int m = 16; m >= 1; m >>= 1)
        mx = fmaxf(mx, __shfl_xor(mx, m));

    float ex = (lane < TOPK) ? expf(sc - mx) : 0.f;
    float sum = ex;
#pragma unroll
    for (int m = 16; m >= 1; m >>= 1)
        sum += __shfl_xor(sum, m);
    float att = ex / sum;

    float acc0 = 0.f, acc1 = 0.f, acc2 = 0.f, acc3 = 0.f, acc4 = 0.f;
    const bool has5 = (lane < EMB - 256);
#pragma unroll 4
    for (int k = 0; k < TOPK; ++k) {
        const float wgt = __shfl(att, k);
        const int   id  = __shfl(nbk, k);
        const float* row = emb + (size_t)id * EMB;
        acc0 = fmaf(wgt, row[lane      ], acc0);
        acc1 = fmaf(wgt, row[lane +  64], acc1);
        acc2 = fmaf(wgt, row[lane + 128], acc2);
        acc3 = fmaf(wgt, row[lane + 192], acc3);
        if (has5) acc4 = fmaf(wgt, row[lane + 256], acc4);
    }

    float* orow = out + (size_t)tok * EMB;
    orow[lane      ] = acc0;
    orow[lane +  64] = acc1;
    orow[lane + 128] = acc2;
    orow[lane + 192] = acc3;
    if (has5) orow[lane + 256] = acc4;
}

extern "C" void kernel_launch(void* const* d_in, const int* in_sizes, int n_in,
                              void* d_out, int out_size, void* d_ws, size_t ws_size,
                              hipStream_t stream) {
    const int*   text      = (const int*)d_in[0];
    const int*   neighbors = (const int*)d_in[1];
    const float* emb       = (const float*)d_in[2];
    const float* A         = (const float*)d_in[3];
    const float* B         = (const float*)d_in[4];
    float*       out       = (float*)d_out;

    char* ws = (char*)d_ws;
    float* S  = (float*)ws;                 // 5 x 400,000 B partial planes
    short* aT = (short*)(ws + 2000000);     // 204,800 B (16B-aligned)

    prep_kernel<<<320, 256, 0, stream>>>(A, aT);
    score_kernel<<<NESL * NVG, 512, 0, stream>>>(emb, aT, B, S);
    attend_kernel<<<NTOK / 4, 256, 0, stream>>>(text, neighbors, emb, S, out);
}

// Round 12
// 133.870 us; speedup vs baseline: 1.3414x; 1.3414x over previous
//
#include <hip/hip_runtime.h>
#include <hip/hip_bf16.h>
#include <math.h>

#define VOCAB 100000
#define TOPK  20
#define EMB   300
#define NTOK  (64*256)
#define NB    1563          // ceil(VOCAB/64) v-tiles
#define NVG   256           // v-groups per e-half

typedef __attribute__((ext_vector_type(8))) short short8;   // 8 bf16 = 4 VGPR
typedef __attribute__((ext_vector_type(4))) short short4v;  // 8 B
typedef __attribute__((ext_vector_type(4))) float f32x4;

static __device__ inline short f2bf(float f) {
    __hip_bfloat16 h = __float2bfloat16(f);
    short s; __builtin_memcpy(&s, &h, 2);
    return s;
}

// ---------------------------------------------------------------------------
// prep: aT[e][d] = bf16(a[d][e]), zero-padded to 320x320.
// ---------------------------------------------------------------------------
__global__ void prep_kernel(const float* __restrict__ A, short* __restrict__ aT)
{
    const int e = blockIdx.x;                 // 0..319
    for (int d = threadIdx.x; d < 320; d += 256) {
        float f = (e < EMB && d < EMB) ? A[(size_t)d * EMB + e] : 0.f;
        aT[e * 320 + d] = f2bf(f);
    }
}

// ---------------------------------------------------------------------------
// score: s[v] = sum_e tanh( emb[v,:] . a[:,e] ) * b[e]  via bf16 MFMA.
// r7 structure (best measured: B-half LDS-stationary, 40-chunk XOR swizzle
// ~0 conflicts, 4 barriers/tile, emb read 2x) with TLP doubled: 1024-thread
// blocks -> 16 waves = 4 waves/SIMD (r7 had 2/SIMD and exposed all latency).
// Waves: 4mg x 2ng x 2kh; wave = 16 rows x 80 cols, K-half 160.
// acc[1][5] = 20 VGPR; bfr single-buffered; total ~100 VGPR << 128 cap
// (r8-r10: the allocator hard-caps at 128 and spills above it).
// kh-exchange scratch = 8 cells x 5 g x 64 lanes x 16 B = 40960 B, exactly
// overlaying the A-tile region (r7 trick; A is dead there, restaged after B4).
// LDS 102400 + 40960 + 512 = 143.9 KB -> 1 block/CU, grid 512 = 2 rounds.
// ---------------------------------------------------------------------------
__global__ __launch_bounds__(1024, 1) void score_kernel(
    const float* __restrict__ emb, const short* __restrict__ aT,
    const float* __restrict__ B, float* __restrict__ S0, float* __restrict__ S1)
{
    __shared__ short8 BsS[160 * 40];     // 102400 B : B e-half, stationary
    __shared__ short8 EsS[64 * 40];      // 40960 B  : A tile / Scr overlay
    __shared__ float  Sred[128];         // 512 B

    const int t  = threadIdx.x;
    const int eh = blockIdx.x & 1;       // e-half
    const int vg = blockIdx.x >> 1;      // 0..255

    // ---- one-time: stage B-half (160 cols x 40 chunks, XOR swizzle).
    // aT is zero-padded to 320x320, so chunks 38/39 stage zeros naturally.
    const short8* aT8 = (const short8*)aT;
#pragma unroll
    for (int j = 0; j < 7; ++j) {
        const int i = t + j * 1024;
        if (i < 6400) {
            const int col = i / 40, q = i - col * 40;
            BsS[col * 40 + (q ^ (col & 7))] = aT8[(eh * 160 + col) * 40 + q];
        }
    }

    const int lid = t & 63;
    const int w   = t >> 6;        // 0..15
    const int kh  = w >> 3;        // k-half 0..1
    const int mg  = (w >> 1) & 3;  // m-tile 0..3 (rows mg*16..mg*16+15)
    const int ng  = w & 1;         // n-group 0..1 (cols ng*80..ng*80+79)
    const int lm  = lid & 15;
    const int lk  = lid >> 4;
    const int kb  = kh * 20;       // k-chunk base
    const int xm  = lm & 7;        // row%8 == col%8 == lm%8 (16-mult offsets)
    const int cell = mg * 2 + ng;  // 0..7

    const int rbA = (mg * 16 + lm) * 40;
    int rbB[5]; float bcol[5];
#pragma unroll
    for (int g = 0; g < 5; ++g) {
        const int col = ng * 80 + g * 16 + lm;     // local col 0..159
        rbB[g] = col * 40;
        const int e = eh * 160 + col;
        bcol[g] = (e < EMB) ? B[e] : 0.f;
    }

    const int ntiles = (NB - vg + NVG - 1) / NVG;  // 6 or 7

    // ---- A prefetch regs: 2368 pair-chunks (3 per thread) + 64 tail float4
    float4 pf[3][2]; float4 pft;

#define ISSUE_PF(TT) do {                                                     \
    const float4* esrc = (const float4*)(emb + (size_t)(TT) * 64 * EMB);      \
    _Pragma("unroll")                                                         \
    for (int j = 0; j < 3; ++j) {                                             \
        const int i = t + j * 1024;                                           \
        const int row = i / 37, c = i - row * 37;                             \
        const bool ok = (i < 2368) && ((TT) * 64 + row < VOCAB);              \
        pf[j][0] = ok ? esrc[row * 75 + c * 2]     : make_float4(0,0,0,0);    \
        pf[j][1] = ok ? esrc[row * 75 + c * 2 + 1] : make_float4(0,0,0,0);    \
    }                                                                         \
    if (t < 64) pft = ((TT) * 64 + t < VOCAB) ? esrc[t * 75 + 74]             \
                                              : make_float4(0,0,0,0);         \
} while (0)

#define STAGE() do {                                                          \
    _Pragma("unroll")                                                         \
    for (int j = 0; j < 3; ++j) {                                             \
        const int i = t + j * 1024;                                           \
        if (i < 2368) {                                                       \
            const int row = i / 37, c = i - row * 37;                         \
            short8 val;                                                       \
            val[0]=f2bf(pf[j][0].x); val[1]=f2bf(pf[j][0].y);                 \
            val[2]=f2bf(pf[j][0].z); val[3]=f2bf(pf[j][0].w);                 \
            val[4]=f2bf(pf[j][1].x); val[5]=f2bf(pf[j][1].y);                 \
            val[6]=f2bf(pf[j][1].z); val[7]=f2bf(pf[j][1].w);                 \
            EsS[row * 40 + (c ^ (row & 7))] = val;                            \
        }                                                                     \
    }                                                                         \
    if (t < 64) {   /* chunk 37: floats 296..299 + zero pad */                \
        short8 v37 = (short8){0,0,0,0,0,0,0,0};                               \
        v37[0]=f2bf(pft.x); v37[1]=f2bf(pft.y);                               \
        v37[2]=f2bf(pft.z); v37[3]=f2bf(pft.w);                               \
        EsS[t * 40 + (37 ^ (t & 7))] = v37;                                   \
    }                                                                         \
    if (t < 128) {  /* chunks 38,39: pure zero pad */                         \
        const int row = t >> 1, q = 38 + (t & 1);                             \
        EsS[row * 40 + (q ^ (row & 7))] = (short8){0,0,0,0,0,0,0,0};          \
    }                                                                         \
} while (0)

    // prologue: tile 0 loaded + staged (B1 in loop covers BsS too)
    ISSUE_PF(vg);
    STAGE();

    for (int tt = 0; tt < ntiles; ++tt) {
        const int v0 = (vg + tt * NVG) * 64;

        __syncthreads();                           // B1: EsS (+BsS) ready
        if (tt + 1 < ntiles) ISSUE_PF(vg + (tt + 1) * NVG);  // T14 issue-early

        // ---- k-loop: 5 steps; afr reg-dbuf, bfr single-buffer, 5 MFMA/step
        f32x4 acc[5];
#pragma unroll
        for (int g = 0; g < 5; ++g) acc[g] = (f32x4){0.f, 0.f, 0.f, 0.f};

        short8 afr[2];
        afr[0] = EsS[rbA + ((kb + lk) ^ xm)];
#pragma unroll
        for (int ks = 0; ks < 5; ++ks) {
            const int cur = ks & 1, nx = cur ^ 1;
            if (ks < 4)
                afr[nx] = EsS[rbA + ((kb + (ks + 1) * 4 + lk) ^ xm)];
            short8 bfr[5];
            const int sx = (kb + ks * 4 + lk) ^ xm;
#pragma unroll
            for (int g = 0; g < 5; ++g) bfr[g] = BsS[rbB[g] + sx];
#pragma unroll
            for (int g = 0; g < 5; ++g)
                acc[g] = __builtin_amdgcn_mfma_f32_16x16x32_bf16(
                             afr[cur], bfr[g], acc[g], 0, 0, 0);
        }
        __syncthreads();                           // B2: EsS/BsS reads done

        // ---- kh-exchange (pre-tanh) via Scr overlaying EsS
        float4* ScrF = (float4*)EsS;               // [5 g][8 cell][64 lane]
        if (kh == 1) {
#pragma unroll
            for (int g = 0; g < 5; ++g)
                ScrF[(g * 8 + cell) * 64 + lid] = *(float4*)&acc[g];
        }
        __syncthreads();                           // B3: partials shipped

        if (kh == 0) {
            float part[4] = {0.f, 0.f, 0.f, 0.f};
#pragma unroll
            for (int g = 0; g < 5; ++g) {
                float4 o = ScrF[(g * 8 + cell) * 64 + lid];
#pragma unroll
                for (int i = 0; i < 4; ++i) {
                    float x  = acc[g][i] + (&o.x)[i];
                    float xc = fminf(fmaxf(x, -15.f), 15.f);
                    float e2 = __expf(2.f * xc);
                    part[i] += __fdividef(e2 - 1.f, e2 + 1.f) * bcol[g];
                }
            }
#pragma unroll
            for (int m = 1; m <= 8; m <<= 1)
#pragma unroll
                for (int i = 0; i < 4; ++i)
                    part[i] += __shfl_xor(part[i], m);
            if (lm == 0) {
#pragma unroll
                for (int i = 0; i < 4; ++i)
                    Sred[ng * 64 + mg * 16 + lk * 4 + i] = part[i];
            }
        }
        __syncthreads();                           // B4: Sred ready, Scr free

        if (t < 64) {
            const int v = v0 + t;
            if (v < VOCAB) {
                float* Sp = eh ? S1 : S0;
                Sp[v] = Sred[t] + Sred[64 + t];
            }
        }
        if (tt + 1 < ntiles) STAGE();              // EsS for next B1
    }
#undef ISSUE_PF
#undef STAGE
}

// ---------------------------------------------------------------------------
// attend: per token gather 20 neighbor scores (S0+S1), softmax, weighted sum.
// ---------------------------------------------------------------------------
__global__ __launch_bounds__(256) void attend_kernel(
    const int* __restrict__ text, const int* __restrict__ neighbors,
    const float* __restrict__ emb, const float* __restrict__ S0,
    const float* __restrict__ S1, float* __restrict__ out)
{
    const int lane = threadIdx.x & 63;
    const int wv   = threadIdx.x >> 6;
    const int tok  = blockIdx.x * 4 + wv;

    const int tid = text[tok];

    int   nbk = 0;
    float sc  = -1e30f;
    if (lane < TOPK) {
        nbk = neighbors[tid * TOPK + lane];
        sc  = S0[nbk] + S1[nbk];
    }

    float mx = sc;
#pragma unroll
    for (int m = 16; m >= 1; m >>= 1)
        mx = fmaxf(mx, __shfl_xor(mx, m));

    float ex = (lane < TOPK) ? expf(sc - mx) : 0.f;
    float sum = ex;
#pragma unroll
    for (int m = 16; m >= 1; m >>= 1)
        sum += __shfl_xor(sum, m);
    float att = ex / sum;

    float acc0 = 0.f, acc1 = 0.f, acc2 = 0.f, acc3 = 0.f, acc4 = 0.f;
    const bool has5 = (lane < EMB - 256);
#pragma unroll 4
    for (int k = 0; k < TOPK; ++k) {
        const float wgt = __shfl(att, k);
        const int   id  = __shfl(nbk, k);
        const float* row = emb + (size_t)id * EMB;
        acc0 = fmaf(wgt, row[lane      ], acc0);
        acc1 = fmaf(wgt, row[lane +  64], acc1);
        acc2 = fmaf(wgt, row[lane + 128], acc2);
        acc3 = fmaf(wgt, row[lane + 192], acc3);
        if (has5) acc4 = fmaf(wgt, row[lane + 256], acc4);
    }

    float* orow = out + (size_t)tok * EMB;
    orow[lane      ] = acc0;
    orow[lane +  64] = acc1;
    orow[lane + 128] = acc2;
    orow[lane + 192] = acc3;
    if (has5) orow[lane + 256] = acc4;
}

extern "C" void kernel_launch(void* const* d_in, const int* in_sizes, int n_in,
                              void* d_out, int out_size, void* d_ws, size_t ws_size,
                              hipStream_t stream) {
    const int*   text      = (const int*)d_in[0];
    const int*   neighbors = (const int*)d_in[1];
    const float* emb       = (const float*)d_in[2];
    const float* A         = (const float*)d_in[3];
    const float* B         = (const float*)d_in[4];
    float*       out       = (float*)d_out;

    char* ws = (char*)d_ws;
    float* S0 = (float*)ws;                 // 400,000 B
    float* S1 = (float*)(ws + 400000);      // 400,000 B
    short* aT = (short*)(ws + 800000);      // 204,800 B (16B-aligned)

    prep_kernel<<<320, 256, 0, stream>>>(A, aT);
    score_kernel<<<2 * NVG, 1024, 0, stream>>>(emb, aT, B, S0, S1);
    attend_kernel<<<NTOK / 4, 256, 0, stream>>>(text, neighbors, emb, S0, S1, out);
}